// Round 3
// baseline (148.733 us; speedup 1.0000x reference)
//
#include <hip/hip_runtime.h>

// Problem constants from the reference: x is (N, T, F) fp32.
constexpr int N_ = 64;
constexpr int T_ = 4096;
constexpr int F_ = 64;
constexpr int F4 = F_ / 4;   // 16 vec4 per (n,t) row

// Native vector type: __builtin_nontemporal_store requires a real vector,
// not HIP's float4 wrapper class.
typedef float fvec4 __attribute__((ext_vector_type(4)));

// Reflect-pad + validity-mask gather.
//   src = rel<0 ? -rel : (rel<L ? rel : 2L-rel-2), clipped to [0, T-1]
//   out[n,t,:] = t < L+p0+p1 ? x[n,src,:] : 0
//
// Layout: 16 threads (one vec4 each) per (n,t) row -> 256B contiguous
// load+store per row. Each thread handles ROWS_PER_THREAD t-rows, so a
// 256-thread block covers 16*ROWS_PER_THREAD consecutive t values and each
// wave stores ROWS_PER_THREAD contiguous 1KB lines.
//
// Stores are non-temporal: out is never re-read, so don't let it evict x
// (64 MB, fully L3-resident; the reflect tail re-reads interior rows).
constexpr int ROWS_PER_THREAD = 2;
constexpr int T_PER_BLOCK = 16 * ROWS_PER_THREAD;   // 32 t-rows per block

__global__ __launch_bounds__(256) void pad_variable_kernel(
    const fvec4* __restrict__ x,
    const int*   __restrict__ lens,
    const int*   __restrict__ pad,   // (2, N): pad[n]=pad0, pad[N_+n]=pad1
    fvec4*       __restrict__ out,
    int Tp)
{
    const int tid  = threadIdx.x;
    const int f4   = tid & (F4 - 1);      // vec4 index within F
    const int trow = tid >> 4;            // 0..15 within block
    const int n    = blockIdx.y;          // wave-uniform -> lens/pad via s_load

    const int L  = lens[n];
    const int p0 = pad[n];
    const int p1 = pad[N_ + n];
    const int Lv = L + p0 + p1;           // valid length

    const fvec4* xn   = x   + (size_t)n * T_ * F4;
    fvec4*       outn = out + (size_t)n * Tp * F4;

    const int t0 = blockIdx.x * T_PER_BLOCK + trow;

#pragma unroll
    for (int r = 0; r < ROWS_PER_THREAD; ++r) {
        const int t = t0 + r * 16;        // wave covers 4 consecutive rows per step
        if (t >= Tp) continue;

        const int rel = t - p0;
        int src = (rel < 0) ? -rel : ((rel < L) ? rel : (2 * L - rel - 2));
        src = min(max(src, 0), T_ - 1);

        fvec4 v = (fvec4)(0.f);
        if (t < Lv) {
            v = xn[(size_t)src * F4 + f4];
        }
        __builtin_nontemporal_store(v, &outn[(size_t)t * F4 + f4]);
    }
}

extern "C" void kernel_launch(void* const* d_in, const int* in_sizes, int n_in,
                              void* d_out, int out_size, void* d_ws, size_t ws_size,
                              hipStream_t stream) {
    const float* x    = (const float*)d_in[0];
    const int*   lens = (const int*)d_in[1];
    const int*   pad  = (const int*)d_in[2];
    // d_in[3] is the Tp scalar on device; recover Tp from out_size instead
    // (out has N*Tp*F elements) so no device->host transfer is needed.
    const int Tp = out_size / (N_ * F_);

    dim3 block(256);
    dim3 grid((Tp + T_PER_BLOCK - 1) / T_PER_BLOCK, N_);
    hipLaunchKernelGGL(pad_variable_kernel, grid, block, 0, stream,
                       (const fvec4*)x, lens, pad, (fvec4*)d_out, Tp);
}

// Round 4
// 145.363 us; speedup vs baseline: 1.0232x; 1.0232x over previous
//
#include <hip/hip_runtime.h>

// Problem constants from the reference: x is (N, T, F) fp32.
constexpr int N_ = 64;
constexpr int T_ = 4096;
constexpr int F_ = 64;
constexpr int F4 = F_ / 4;   // 16 vec4 per (n,t) row

typedef float fvec4 __attribute__((ext_vector_type(4)));

// Reflect-pad + validity-mask gather.
//   src = rel<0 ? -rel : (rel<L ? rel : 2L-rel-2), clipped to [0, T-1]
//   out[n,t,:] = t < L+p0+p1 ? x[n,src,:] : 0
//
// Layout: 16 threads (one vec4 each) per (n,t) row -> 256B contiguous
// load+store per row; each wave covers 4 consecutive t rows (1KB contiguous
// store) per iteration. ROWS_PER_THREAD=2 halves the grid vs 1 row/thread.
//
// Stores are plain cached stores: NT stores measured +3.5us (out doesn't fit
// L2 either way; x residency is handled by the 256MB L3, not L2).
constexpr int ROWS_PER_THREAD = 2;
constexpr int T_PER_BLOCK = 16 * ROWS_PER_THREAD;   // 32 t-rows per block

__global__ __launch_bounds__(256) void pad_variable_kernel(
    const fvec4* __restrict__ x,
    const int*   __restrict__ lens,
    const int*   __restrict__ pad,   // (2, N): pad[n]=pad0, pad[N_+n]=pad1
    fvec4*       __restrict__ out,
    int Tp)
{
    const int tid  = threadIdx.x;
    const int f4   = tid & (F4 - 1);      // vec4 index within F
    const int trow = tid >> 4;            // 0..15 within block
    const int n    = blockIdx.y;          // wave-uniform -> lens/pad via s_load

    const int L  = lens[n];
    const int p0 = pad[n];
    const int p1 = pad[N_ + n];
    const int Lv = L + p0 + p1;           // valid length

    const fvec4* xn   = x   + (size_t)n * T_ * F4;
    fvec4*       outn = out + (size_t)n * Tp * F4;

    const int t0 = blockIdx.x * T_PER_BLOCK + trow;

#pragma unroll
    for (int r = 0; r < ROWS_PER_THREAD; ++r) {
        const int t = t0 + r * 16;
        if (t >= Tp) continue;

        const int rel = t - p0;
        int src = (rel < 0) ? -rel : ((rel < L) ? rel : (2 * L - rel - 2));
        src = min(max(src, 0), T_ - 1);

        fvec4 v = (fvec4)(0.f);
        if (t < Lv) {
            v = xn[(size_t)src * F4 + f4];
        }
        outn[(size_t)t * F4 + f4] = v;
    }
}

extern "C" void kernel_launch(void* const* d_in, const int* in_sizes, int n_in,
                              void* d_out, int out_size, void* d_ws, size_t ws_size,
                              hipStream_t stream) {
    const float* x    = (const float*)d_in[0];
    const int*   lens = (const int*)d_in[1];
    const int*   pad  = (const int*)d_in[2];
    // Recover Tp from out_size (out has N*Tp*F elements) — no D2H read needed.
    const int Tp = out_size / (N_ * F_);

    dim3 block(256);
    dim3 grid((Tp + T_PER_BLOCK - 1) / T_PER_BLOCK, N_);
    hipLaunchKernelGGL(pad_variable_kernel, grid, block, 0, stream,
                       (const fvec4*)x, lens, pad, (fvec4*)d_out, Tp);
}